// Round 2
// baseline (653.285 us; speedup 1.0000x reference)
//
#include <hip/hip_runtime.h>
#include <math.h>

#define Bn 8
#define Cn 1152
#define Hn 32
#define Wn 32
#define Nn 1024  // Hn*Wn

// Small per-(b,j)/per-(b,i) state. Fully overwritten every call.
__device__ float g_dy[Bn * Nn];
__device__ float g_y0[Bn * Nn];
__device__ float g_invn[Bn * Nn];
__device__ float g_rmax[Bn * Nn];
__device__ float g_rsum[Bn * Nn];
__device__ float g_cmax[Bn * Nn];
__device__ float g_csum[Bn * Nn];

__device__ inline void inv3(const float* M, float* o) {
    float a = M[0], b = M[1], c = M[2];
    float d = M[3], e = M[4], f = M[5];
    float g = M[6], h = M[7], i = M[8];
    float A0 = (e * i - f * h);
    float A1 = -(d * i - f * g);
    float A2 = (d * h - e * g);
    float det = a * A0 + b * A1 + c * A2;
    float inv = 1.0f / det;
    o[0] = A0 * inv;
    o[1] = -(b * i - c * h) * inv;
    o[2] = (b * f - c * e) * inv;
    o[3] = A1 * inv;
    o[4] = (a * i - c * g) * inv;
    o[5] = -(a * f - c * d) * inv;
    o[6] = A2 * inv;
    o[7] = -(a * h - b * g) * inv;
    o[8] = (a * e - b * d) * inv;
}

__device__ inline void mm3(const float* X, const float* Y, float* Z) {
    for (int r = 0; r < 3; r++)
        for (int c = 0; c < 3; c++)
            Z[r * 3 + c] = X[r * 3 + 0] * Y[0 * 3 + c] + X[r * 3 + 1] * Y[1 * 3 + c] +
                           X[r * 3 + 2] * Y[2 * 3 + c];
}

// One block per batch: thread 0 builds F (SVD is a rank-2 no-op: skew(t)@R
// already has singular values (|t|,|t|,0)); then all threads compute per-j
// epipolar line params.
__global__ void setup_kernel(const float* __restrict__ K1, const float* __restrict__ K2,
                             const float* __restrict__ R, const float* __restrict__ t) {
    __shared__ float Fs[9];
    int b = blockIdx.x;
    if (threadIdx.x == 0) {
        float t0 = t[b * 3 + 0], t1 = t[b * 3 + 1], t2 = t[b * 3 + 2];
        float S[9] = {0.0f, -t2, t1, t2, 0.0f, -t0, -t1, t0, 0.0f};
        float E[9];
        mm3(S, &R[b * 9], E);
        float iK1[9], iK2[9];
        inv3(&K1[b * 9], iK1);
        inv3(&K2[b * 9], iK2);
        float iK2T[9] = {iK2[0], iK2[3], iK2[6], iK2[1], iK2[4], iK2[7], iK2[2], iK2[5], iK2[8]};
        float T[9], F[9];
        mm3(iK2T, E, T);
        mm3(T, iK1, F);
        for (int k = 0; k < 9; k++) Fs[k] = F[k];
    }
    __syncthreads();
    for (int j = threadIdx.x; j < Nn; j += blockDim.x) {
        float ix = (float)(j >> 5);  // meshgrid 'ij': ix = j // W
        float iy = (float)(j & 31);  // iy = j % W
        float l0 = Fs[0] * ix + Fs[1] * iy + Fs[2];
        float l1 = Fs[3] * ix + Fs[4] * iy + Fs[5];
        float l2 = Fs[6] * ix + Fs[7] * iy + Fs[8];
        l0 = l0 / l2;
        l1 = l1 / l2;
        float y0 = -1.0f / l1;                      // -lines[2]/lines[1], lines[2]==1
        float y1 = -(1.0f + l0 * 32.0f) / l1;       // -(1 + l0*W)/l1
        float dy = y0 - y1;
        float dn = sqrtf(1024.0f + dy * dy);        // sqrt(W^2 + dy^2)
        g_dy[b * Nn + j] = dy;
        g_y0[b * Nn + j] = y0;
        g_invn[b * Nn + j] = 1.0f / dn;
    }
}

// d_epi recompute: |ix_i*dy_j + W*(iy_i - y0_j)| * invn_j  (cross z-component only;
// x,y components are exactly zero in the reference)
__device__ inline float zval(float ix, float iy, float dy, float y0, float invn) {
    float d = fabsf(ix * dy + 32.0f * (iy - y0)) * invn;
    return 5.0f * (d - 0.1f);
}

// Row softmax stats (over j) for each (b, i)
__global__ void rowstats_kernel() {
    int b = blockIdx.x >> 10;
    int i = blockIdx.x & 1023;
    float ix = (float)(i >> 5), iy = (float)(i & 31);
    int t = threadIdx.x;
    float z[4];
    float m = -INFINITY;
    for (int k = 0; k < 4; k++) {
        int j = t + k * 256;
        z[k] = zval(ix, iy, g_dy[b * Nn + j], g_y0[b * Nn + j], g_invn[b * Nn + j]);
        m = fmaxf(m, z[k]);
    }
    __shared__ float red[256];
    red[t] = m;
    __syncthreads();
    for (int s = 128; s > 0; s >>= 1) {
        if (t < s) red[t] = fmaxf(red[t], red[t + s]);
        __syncthreads();
    }
    float rmax = red[0];
    __syncthreads();
    float sum = 0.0f;
    for (int k = 0; k < 4; k++) sum += expf(z[k] - rmax);
    red[t] = sum;
    __syncthreads();
    for (int s = 128; s > 0; s >>= 1) {
        if (t < s) red[t] += red[t + s];
        __syncthreads();
    }
    if (t == 0) {
        g_rmax[b * Nn + i] = rmax;
        g_rsum[b * Nn + i] = red[0];
    }
}

// Column softmax stats (over i) for each (b, j), on w = 1 - softmax_row
__global__ void colstats_kernel() {
    int b = blockIdx.x >> 10;
    int j = blockIdx.x & 1023;
    float dy = g_dy[b * Nn + j], y0 = g_y0[b * Nn + j], invn = g_invn[b * Nn + j];
    int t = threadIdx.x;
    float w[4];
    float m = -INFINITY;
    for (int k = 0; k < 4; k++) {
        int i = t + k * 256;
        float ix = (float)(i >> 5), iy = (float)(i & 31);
        float z = zval(ix, iy, dy, y0, invn);
        float s1 = expf(z - g_rmax[b * Nn + i]) / g_rsum[b * Nn + i];
        w[k] = 1.0f - s1;
        m = fmaxf(m, w[k]);
    }
    __shared__ float red[256];
    red[t] = m;
    __syncthreads();
    for (int s = 128; s > 0; s >>= 1) {
        if (t < s) red[t] = fmaxf(red[t], red[t + s]);
        __syncthreads();
    }
    float cmax = red[0];
    __syncthreads();
    float sum = 0.0f;
    for (int k = 0; k < 4; k++) sum += expf(w[k] - cmax);
    red[t] = sum;
    __syncthreads();
    for (int s = 128; s > 0; s >>= 1) {
        if (t < s) red[t] += red[t + s];
        __syncthreads();
    }
    if (t == 0) {
        g_cmax[b * Nn + j] = cmax;
        g_csum[b * Nn + j] = red[0];
    }
}

// out[b, i, c] = sum_j A[b,i,j] * f_src[b,c,j];  flat out index = (b*N + i)*C + c
#define TM 64
#define TC 64
#define TK 16
#define PAD 4

__launch_bounds__(256) __global__
void attn_matmul_kernel(const float* __restrict__ f_src, float* __restrict__ out) {
    int b = blockIdx.z;
    int i0 = blockIdx.y * TM;
    int c0 = blockIdx.x * TC;
    __shared__ float As[TK][TM + PAD];
    __shared__ float Bs[TK][TC + PAD];
    __shared__ float s_rmax[TM], s_rsum[TM];
    __shared__ float s_dy[TK], s_y0[TK], s_invn[TK], s_cmax[TK], s_csum[TK];
    int t = threadIdx.x;
    int tx = t & 15;   // c quad
    int ty = t >> 4;   // i quad
    if (t < TM) {
        s_rmax[t] = g_rmax[b * Nn + i0 + t];
        s_rsum[t] = g_rsum[b * Nn + i0 + t];
    }
    float acc[4][4] = {};
    for (int j0 = 0; j0 < Nn; j0 += TK) {
        __syncthreads();  // prev tile consumed (also orders s_rmax init)
        if (t < TK) {
            s_dy[t] = g_dy[b * Nn + j0 + t];
            s_y0[t] = g_y0[b * Nn + j0 + t];
            s_invn[t] = g_invn[b * Nn + j0 + t];
            s_cmax[t] = g_cmax[b * Nn + j0 + t];
            s_csum[t] = g_csum[b * Nn + j0 + t];
        }
        __syncthreads();
        // A tile (64 i x 16 k), recomputed on the fly: 2 expf per element
        for (int e = t; e < TM * TK; e += 256) {
            int ii = e >> 4, k = e & 15;
            float ix = (float)((i0 + ii) >> 5), iy = (float)((i0 + ii) & 31);
            float z = zval(ix, iy, s_dy[k], s_y0[k], s_invn[k]);
            float w = 1.0f - expf(z - s_rmax[ii]) / s_rsum[ii];
            As[k][ii] = expf(w - s_cmax[k]) / s_csum[k];
        }
        // B tile: Bs[k][cc] = f_src[b, c0+cc, j0+k]
        for (int e = t; e < TK * TC; e += 256) {
            int cc = e >> 4, k = e & 15;
            Bs[k][cc] = f_src[(size_t)b * Cn * Nn + (size_t)(c0 + cc) * Nn + j0 + k];
        }
        __syncthreads();
#pragma unroll
        for (int k = 0; k < TK; k++) {
            float4 av = *(const float4*)&As[k][ty * 4];
            float4 bv = *(const float4*)&Bs[k][tx * 4];
            float a[4] = {av.x, av.y, av.z, av.w};
            float bb[4] = {bv.x, bv.y, bv.z, bv.w};
#pragma unroll
            for (int r = 0; r < 4; r++)
#pragma unroll
                for (int c = 0; c < 4; c++) acc[r][c] += a[r] * bb[c];
        }
    }
#pragma unroll
    for (int r = 0; r < 4; r++) {
        int i = i0 + ty * 4 + r;
        size_t base = ((size_t)b * Nn + i) * Cn + c0 + tx * 4;
        float4 v = make_float4(acc[r][0], acc[r][1], acc[r][2], acc[r][3]);
        *(float4*)&out[base] = v;
    }
}

extern "C" void kernel_launch(void* const* d_in, const int* in_sizes, int n_in,
                              void* d_out, int out_size, void* d_ws, size_t ws_size,
                              hipStream_t stream) {
    (void)in_sizes; (void)n_in; (void)d_ws; (void)ws_size; (void)out_size;
    const float* f_src = (const float*)d_in[1];  // d_in[0] = f_tar is unused by the reference
    const float* K1 = (const float*)d_in[2];
    const float* K2 = (const float*)d_in[3];
    const float* R = (const float*)d_in[4];
    const float* t = (const float*)d_in[5];
    float* out = (float*)d_out;

    setup_kernel<<<dim3(Bn), dim3(256), 0, stream>>>(K1, K2, R, t);
    rowstats_kernel<<<dim3(Bn * Nn), dim3(256), 0, stream>>>();
    colstats_kernel<<<dim3(Bn * Nn), dim3(256), 0, stream>>>();
    attn_matmul_kernel<<<dim3(Cn / TC, Nn / TM, Bn), dim3(256), 0, stream>>>(f_src, out);
}

// Round 3
// 218.923 us; speedup vs baseline: 2.9841x; 2.9841x over previous
//
#include <hip/hip_runtime.h>
#include <hip/hip_bf16.h>
#include <math.h>

#define Bn 8
#define Cn 1152
#define Hn 32
#define Wn 32
#define Nn 1024  // Hn*Wn

typedef short short8 __attribute__((ext_vector_type(8)));
typedef float f32x4 __attribute__((ext_vector_type(4)));

// Per-(b,j)/per-(b,i) softmax state. Fully overwritten every call.
__device__ float g_dy[Bn * Nn];
__device__ float g_y0[Bn * Nn];
__device__ float g_invn[Bn * Nn];
__device__ float g_rmax[Bn * Nn];
__device__ float g_rsum[Bn * Nn];
__device__ float g_cmax[Bn * Nn];
__device__ float g_csum[Bn * Nn];
// bf16 operands for the MFMA GEMM. Fully overwritten every call.
__device__ unsigned short g_A[(size_t)Bn * Nn * Nn];        // A[b][i][j]
__device__ unsigned short g_fb[(size_t)Bn * Cn * Nn];       // f_src[b][c][j] in bf16

__device__ inline unsigned short f2bf(float x) {
    __hip_bfloat16 h = __float2bfloat16(x);
    unsigned short u;
    __builtin_memcpy(&u, &h, 2);
    return u;
}

__device__ inline void inv3(const float* M, float* o) {
    float a = M[0], b = M[1], c = M[2];
    float d = M[3], e = M[4], f = M[5];
    float g = M[6], h = M[7], i = M[8];
    float A0 = (e * i - f * h);
    float A1 = -(d * i - f * g);
    float A2 = (d * h - e * g);
    float det = a * A0 + b * A1 + c * A2;
    float inv = 1.0f / det;
    o[0] = A0 * inv;
    o[1] = -(b * i - c * h) * inv;
    o[2] = (b * f - c * e) * inv;
    o[3] = A1 * inv;
    o[4] = (a * i - c * g) * inv;
    o[5] = -(a * f - c * d) * inv;
    o[6] = A2 * inv;
    o[7] = -(a * h - b * g) * inv;
    o[8] = (a * e - b * d) * inv;
}

__device__ inline void mm3(const float* X, const float* Y, float* Z) {
    for (int r = 0; r < 3; r++)
        for (int c = 0; c < 3; c++)
            Z[r * 3 + c] = X[r * 3 + 0] * Y[0 * 3 + c] + X[r * 3 + 1] * Y[1 * 3 + c] +
                           X[r * 3 + 2] * Y[2 * 3 + c];
}

// F build (SVD is a rank-2 no-op: skew(t)@R has singvals (|t|,|t|,0)) + per-j line params.
__global__ void setup_kernel(const float* __restrict__ K1, const float* __restrict__ K2,
                             const float* __restrict__ R, const float* __restrict__ t) {
    __shared__ float Fs[9];
    int b = blockIdx.x;
    if (threadIdx.x == 0) {
        float t0 = t[b * 3 + 0], t1 = t[b * 3 + 1], t2 = t[b * 3 + 2];
        float S[9] = {0.0f, -t2, t1, t2, 0.0f, -t0, -t1, t0, 0.0f};
        float E[9];
        mm3(S, &R[b * 9], E);
        float iK1[9], iK2[9];
        inv3(&K1[b * 9], iK1);
        inv3(&K2[b * 9], iK2);
        float iK2T[9] = {iK2[0], iK2[3], iK2[6], iK2[1], iK2[4], iK2[7], iK2[2], iK2[5], iK2[8]};
        float T[9], F[9];
        mm3(iK2T, E, T);
        mm3(T, iK1, F);
        for (int k = 0; k < 9; k++) Fs[k] = F[k];
    }
    __syncthreads();
    for (int j = threadIdx.x; j < Nn; j += blockDim.x) {
        float ix = (float)(j >> 5);
        float iy = (float)(j & 31);
        float l0 = Fs[0] * ix + Fs[1] * iy + Fs[2];
        float l1 = Fs[3] * ix + Fs[4] * iy + Fs[5];
        float l2 = Fs[6] * ix + Fs[7] * iy + Fs[8];
        l0 = l0 / l2;
        l1 = l1 / l2;
        float y0 = -1.0f / l1;
        float y1 = -(1.0f + l0 * 32.0f) / l1;
        float dy = y0 - y1;
        float dn = sqrtf(1024.0f + dy * dy);
        g_dy[b * Nn + j] = dy;
        g_y0[b * Nn + j] = y0;
        g_invn[b * Nn + j] = 1.0f / dn;
    }
}

__device__ inline float zval(float ix, float iy, float dy, float y0, float invn) {
    float d = fabsf(ix * dy + 32.0f * (iy - y0)) * invn;
    return 5.0f * (d - 0.1f);
}

// Row softmax stats (over j) for each (b, i)
__global__ void rowstats_kernel() {
    int b = blockIdx.x >> 10;
    int i = blockIdx.x & 1023;
    float ix = (float)(i >> 5), iy = (float)(i & 31);
    int t = threadIdx.x;
    float z[4];
    float m = -INFINITY;
    for (int k = 0; k < 4; k++) {
        int j = t + k * 256;
        z[k] = zval(ix, iy, g_dy[b * Nn + j], g_y0[b * Nn + j], g_invn[b * Nn + j]);
        m = fmaxf(m, z[k]);
    }
    __shared__ float red[256];
    red[t] = m;
    __syncthreads();
    for (int s = 128; s > 0; s >>= 1) {
        if (t < s) red[t] = fmaxf(red[t], red[t + s]);
        __syncthreads();
    }
    float rmax = red[0];
    __syncthreads();
    float sum = 0.0f;
    for (int k = 0; k < 4; k++) sum += expf(z[k] - rmax);
    red[t] = sum;
    __syncthreads();
    for (int s = 128; s > 0; s >>= 1) {
        if (t < s) red[t] += red[t + s];
        __syncthreads();
    }
    if (t == 0) {
        g_rmax[b * Nn + i] = rmax;
        g_rsum[b * Nn + i] = red[0];
    }
}

// Column softmax stats (over i) for each (b, j), on w = 1 - softmax_row
__global__ void colstats_kernel() {
    int b = blockIdx.x >> 10;
    int j = blockIdx.x & 1023;
    float dy = g_dy[b * Nn + j], y0 = g_y0[b * Nn + j], invn = g_invn[b * Nn + j];
    int t = threadIdx.x;
    float w[4];
    float m = -INFINITY;
    for (int k = 0; k < 4; k++) {
        int i = t + k * 256;
        float ix = (float)(i >> 5), iy = (float)(i & 31);
        float z = zval(ix, iy, dy, y0, invn);
        float s1 = expf(z - g_rmax[b * Nn + i]) / g_rsum[b * Nn + i];
        w[k] = 1.0f - s1;
        m = fmaxf(m, w[k]);
    }
    __shared__ float red[256];
    red[t] = m;
    __syncthreads();
    for (int s = 128; s > 0; s >>= 1) {
        if (t < s) red[t] = fmaxf(red[t], red[t + s]);
        __syncthreads();
    }
    float cmax = red[0];
    __syncthreads();
    float sum = 0.0f;
    for (int k = 0; k < 4; k++) sum += expf(w[k] - cmax);
    red[t] = sum;
    __syncthreads();
    for (int s = 128; s > 0; s >>= 1) {
        if (t < s) red[t] += red[t + s];
        __syncthreads();
    }
    if (t == 0) {
        g_cmax[b * Nn + j] = cmax;
        g_csum[b * Nn + j] = red[0];
    }
}

// Materialize A[b][i][j] in bf16 (one pass — kills the per-c-tile exp recompute)
__global__ void precompute_A_kernel() {
    int idx = blockIdx.x * 256 + threadIdx.x;  // 8*1024*256 threads, 4 j's each
    int j4 = idx & 255;
    int i = (idx >> 8) & 1023;
    int b = idx >> 18;
    int base = b * Nn;
    float rmax = g_rmax[base + i], rsum = g_rsum[base + i];
    float ix = (float)(i >> 5), iy = (float)(i & 31);
    int j = j4 * 4;
    float4 dy = *(const float4*)&g_dy[base + j];
    float4 y0 = *(const float4*)&g_y0[base + j];
    float4 invn = *(const float4*)&g_invn[base + j];
    float4 cmax = *(const float4*)&g_cmax[base + j];
    float4 csum = *(const float4*)&g_csum[base + j];
    float w0 = 1.0f - expf(zval(ix, iy, dy.x, y0.x, invn.x) - rmax) / rsum;
    float w1 = 1.0f - expf(zval(ix, iy, dy.y, y0.y, invn.y) - rmax) / rsum;
    float w2 = 1.0f - expf(zval(ix, iy, dy.z, y0.z, invn.z) - rmax) / rsum;
    float w3 = 1.0f - expf(zval(ix, iy, dy.w, y0.w, invn.w) - rmax) / rsum;
    ushort4 u;
    u.x = f2bf(expf(w0 - cmax.x) / csum.x);
    u.y = f2bf(expf(w1 - cmax.y) / csum.y);
    u.z = f2bf(expf(w2 - cmax.z) / csum.z);
    u.w = f2bf(expf(w3 - cmax.w) / csum.w);
    *(ushort4*)&g_A[((size_t)b * Nn + i) * Nn + j] = u;
}

// f_src fp32 -> bf16 (layout preserved: [b][c][j])
__global__ void convert_fsrc_kernel(const float* __restrict__ f) {
    size_t idx = (size_t)blockIdx.x * 256 + threadIdx.x;  // 9216*256 threads, 4 each
    size_t off = idx * 4;
    float4 v = *(const float4*)(f + off);
    ushort4 u;
    u.x = f2bf(v.x);
    u.y = f2bf(v.y);
    u.z = f2bf(v.z);
    u.w = f2bf(v.w);
    *(ushort4*)&g_fb[off] = u;
}

// out[b,i,c] = sum_j A[b,i,j] * fsrc_bf16[b,c,j]  — both operands K(j)-contiguous.
// 128(i) x 128(c) tile, BK=32, 4 waves, each wave 64x64 via 4x4 mfma_16x16x32.
// k-quad XOR swizzle breaks the 64B-row-stride bank aliasing; global_load_lds
// LDS side stays lane-contiguous (swizzle applied to the GLOBAL address).
#define BM 128
#define BNc 128
#define BK 32

__launch_bounds__(256) __global__ void gemm_kernel(float* __restrict__ out) {
    __shared__ unsigned short As[BM * BK];
    __shared__ unsigned short Bs[BNc * BK];
    int b = blockIdx.z;
    int i0 = blockIdx.y * BM;
    int c0 = blockIdx.x * BNc;
    int t = threadIdx.x;
    int w = t >> 6, L = t & 63;
    int wm = w >> 1, wn = w & 1;
    const unsigned short* Ab = g_A + (size_t)b * Nn * Nn + (size_t)i0 * Nn;
    const unsigned short* Fb = g_fb + (size_t)b * Cn * Nn + (size_t)c0 * Nn;
    f32x4 acc[4][4] = {};
    for (int kt = 0; kt < Nn; kt += BK) {
        __syncthreads();  // previous tile consumed
#pragma unroll
        for (int h = 0; h < 2; h++) {
            int chunk = (h * 4 + w) * 64 + L;     // 0..511, 16B each
            int r = chunk >> 2;                   // tile row 0..127
            int gq = (chunk & 3) ^ ((r >> 1) & 3);  // swizzled global k-quad
            const unsigned short* ga = Ab + (size_t)r * Nn + kt + gq * 8;
            const unsigned short* gb = Fb + (size_t)r * Nn + kt + gq * 8;
            __builtin_amdgcn_global_load_lds(
                (const __attribute__((address_space(1))) unsigned int*)ga,
                (__attribute__((address_space(3))) unsigned int*)(As + chunk * 8), 16, 0, 0);
            __builtin_amdgcn_global_load_lds(
                (const __attribute__((address_space(1))) unsigned int*)gb,
                (__attribute__((address_space(3))) unsigned int*)(Bs + chunk * 8), 16, 0, 0);
        }
        __syncthreads();  // vmcnt(0) drain + barrier
        short8 af[4], bf[4];
        int lrow = L & 15, quad = L >> 4;
#pragma unroll
        for (int mt = 0; mt < 4; mt++) {
            int r = wm * 64 + mt * 16 + lrow;
            int q = quad ^ ((r >> 1) & 3);
            af[mt] = *(const short8*)(As + r * BK + q * 8);
        }
#pragma unroll
        for (int nt = 0; nt < 4; nt++) {
            int r = wn * 64 + nt * 16 + lrow;
            int q = quad ^ ((r >> 1) & 3);
            bf[nt] = *(const short8*)(Bs + r * BK + q * 8);
        }
#pragma unroll
        for (int mt = 0; mt < 4; mt++)
#pragma unroll
            for (int nt = 0; nt < 4; nt++)
                acc[mt][nt] =
                    __builtin_amdgcn_mfma_f32_16x16x32_bf16(af[mt], bf[nt], acc[mt][nt], 0, 0, 0);
    }
    // Epilogue: D col=lane&15, row=(lane>>4)*4+reg  [m89-verified]
    int col = L & 15, quad = L >> 4;
#pragma unroll
    for (int mt = 0; mt < 4; mt++)
#pragma unroll
        for (int rg = 0; rg < 4; rg++) {
            int i = i0 + wm * 64 + mt * 16 + quad * 4 + rg;
            float* orow = out + ((size_t)b * Nn + i) * Cn + c0 + wn * 64;
#pragma unroll
            for (int nt = 0; nt < 4; nt++) orow[nt * 16 + col] = acc[mt][nt][rg];
        }
}

extern "C" void kernel_launch(void* const* d_in, const int* in_sizes, int n_in,
                              void* d_out, int out_size, void* d_ws, size_t ws_size,
                              hipStream_t stream) {
    (void)in_sizes; (void)n_in; (void)d_ws; (void)ws_size; (void)out_size;
    const float* f_src = (const float*)d_in[1];  // d_in[0] = f_tar unused by reference
    const float* K1 = (const float*)d_in[2];
    const float* K2 = (const float*)d_in[3];
    const float* R = (const float*)d_in[4];
    const float* t = (const float*)d_in[5];
    float* out = (float*)d_out;

    setup_kernel<<<dim3(Bn), dim3(256), 0, stream>>>(K1, K2, R, t);
    rowstats_kernel<<<dim3(Bn * Nn), dim3(256), 0, stream>>>();
    colstats_kernel<<<dim3(Bn * Nn), dim3(256), 0, stream>>>();
    convert_fsrc_kernel<<<dim3((Bn * Cn * Nn) / 1024), dim3(256), 0, stream>>>(f_src);
    precompute_A_kernel<<<dim3((Bn * Nn * Nn) / 1024), dim3(256), 0, stream>>>();
    gemm_kernel<<<dim3(Cn / BNc, Nn / BM, Bn), dim3(256), 0, stream>>>(out);
}

// Round 4
// 190.512 us; speedup vs baseline: 3.4291x; 1.1491x over previous
//
#include <hip/hip_runtime.h>
#include <hip/hip_bf16.h>
#include <math.h>

#define Bn 8
#define Cn 1152
#define Hn 32
#define Wn 32
#define Nn 1024  // Hn*Wn

typedef short short8 __attribute__((ext_vector_type(8)));
typedef float f32x4 __attribute__((ext_vector_type(4)));

// Per-(b,j)/per-(b,i) softmax state. Fully overwritten every call.
__device__ float g_dy[Bn * Nn];
__device__ float g_y0[Bn * Nn];
__device__ float g_invn[Bn * Nn];
__device__ float g_rmax[Bn * Nn];
__device__ float g_rsuminv[Bn * Nn];
__device__ float g_csum[Bn * Nn];   // zeroed in setup_kernel each call
// bf16 operands for the MFMA GEMM. Fully overwritten every call.
__device__ unsigned short g_A[(size_t)Bn * Nn * Nn];   // E[b][i][j] = exp(w) (unnormalized)
__device__ unsigned short g_fb[(size_t)Bn * Cn * Nn];  // f_src[b][c][j] * (1/csum[b][j]) in bf16

__device__ inline unsigned short f2bf(float x) {
    __hip_bfloat16 h = __float2bfloat16(x);
    unsigned short u;
    __builtin_memcpy(&u, &h, 2);
    return u;
}

__device__ inline void inv3(const float* M, float* o) {
    float a = M[0], b = M[1], c = M[2];
    float d = M[3], e = M[4], f = M[5];
    float g = M[6], h = M[7], i = M[8];
    float A0 = (e * i - f * h);
    float A1 = -(d * i - f * g);
    float A2 = (d * h - e * g);
    float det = a * A0 + b * A1 + c * A2;
    float inv = 1.0f / det;
    o[0] = A0 * inv;
    o[1] = -(b * i - c * h) * inv;
    o[2] = (b * f - c * e) * inv;
    o[3] = A1 * inv;
    o[4] = (a * i - c * g) * inv;
    o[5] = -(a * f - c * d) * inv;
    o[6] = A2 * inv;
    o[7] = -(a * h - b * g) * inv;
    o[8] = (a * e - b * d) * inv;
}

__device__ inline void mm3(const float* X, const float* Y, float* Z) {
    for (int r = 0; r < 3; r++)
        for (int c = 0; c < 3; c++)
            Z[r * 3 + c] = X[r * 3 + 0] * Y[0 * 3 + c] + X[r * 3 + 1] * Y[1 * 3 + c] +
                           X[r * 3 + 2] * Y[2 * 3 + c];
}

// F build (SVD is a rank-2 no-op: skew(t)@R has singvals (|t|,|t|,0)) + per-j line
// params + csum zeroing. One block per batch (blockIdx.x = b = XCD).
__global__ void setup_kernel(const float* __restrict__ K1, const float* __restrict__ K2,
                             const float* __restrict__ R, const float* __restrict__ t) {
    __shared__ float Fs[9];
    int b = blockIdx.x;
    for (int j = threadIdx.x; j < Nn; j += blockDim.x) g_csum[b * Nn + j] = 0.0f;
    if (threadIdx.x == 0) {
        float t0 = t[b * 3 + 0], t1 = t[b * 3 + 1], t2 = t[b * 3 + 2];
        float S[9] = {0.0f, -t2, t1, t2, 0.0f, -t0, -t1, t0, 0.0f};
        float E[9];
        mm3(S, &R[b * 9], E);
        float iK1[9], iK2[9];
        inv3(&K1[b * 9], iK1);
        inv3(&K2[b * 9], iK2);
        float iK2T[9] = {iK2[0], iK2[3], iK2[6], iK2[1], iK2[4], iK2[7], iK2[2], iK2[5], iK2[8]};
        float T[9], F[9];
        mm3(iK2T, E, T);
        mm3(T, iK1, F);
        for (int k = 0; k < 9; k++) Fs[k] = F[k];
    }
    __syncthreads();
    for (int j = threadIdx.x; j < Nn; j += blockDim.x) {
        float ix = (float)(j >> 5);
        float iy = (float)(j & 31);
        float l0 = Fs[0] * ix + Fs[1] * iy + Fs[2];
        float l1 = Fs[3] * ix + Fs[4] * iy + Fs[5];
        float l2 = Fs[6] * ix + Fs[7] * iy + Fs[8];
        l0 = l0 / l2;
        l1 = l1 / l2;
        float y0 = -1.0f / l1;
        float y1 = -(1.0f + l0 * 32.0f) / l1;
        float dy = y0 - y1;
        float dn = sqrtf(1024.0f + dy * dy);
        g_dy[b * Nn + j] = dy;
        g_y0[b * Nn + j] = y0;
        g_invn[b * Nn + j] = 1.0f / dn;
    }
}

__device__ inline float zval(float ix, float iy, float dy, float y0, float invn) {
    float d = fabsf(ix * dy + 32.0f * (iy - y0)) * invn;
    return 5.0f * (d - 0.1f);
}

// Row softmax stats (over j), one wave per row i. Grid 2048x256: lin&7 = b = XCD.
__global__ void rowstats_kernel() {
    int lin = blockIdx.x;
    int b = lin & 7;
    int seg = lin >> 3;               // 0..255
    int wv = threadIdx.x >> 6;        // 0..3
    int lane = threadIdx.x & 63;
    int i = seg * 4 + wv;
    float ix = (float)(i >> 5), iy = (float)(i & 31);
    int base = b * Nn;
    float z[16];
    float m = -INFINITY;
#pragma unroll
    for (int k = 0; k < 16; k++) {
        int j = lane + k * 64;
        z[k] = zval(ix, iy, g_dy[base + j], g_y0[base + j], g_invn[base + j]);
        m = fmaxf(m, z[k]);
    }
#pragma unroll
    for (int o = 32; o > 0; o >>= 1) m = fmaxf(m, __shfl_xor(m, o, 64));
    float s = 0.0f;
#pragma unroll
    for (int k = 0; k < 16; k++) s += __expf(z[k] - m);
#pragma unroll
    for (int o = 32; o > 0; o >>= 1) s += __shfl_xor(s, o, 64);
    if (lane == 0) {
        g_rmax[base + i] = m;
        g_rsuminv[base + i] = 1.0f / s;
    }
}

// Fused column pass: E = exp(1 - rowsoftmax) written as bf16 (unnormalized A) +
// per-j column sums via atomics. No max-subtraction needed: w in (0,1).
// Grid 256 blocks: lin&7 = b = XCD; r>>3: jc = r&3 (256-j chunk), iseg = r>>2 (128 i's).
__global__ void colE_kernel() {
    int lin = blockIdx.x;
    int b = lin & 7;
    int r = lin >> 3;
    int jc = r & 3;
    int iseg = r >> 2;
    int t = threadIdx.x;
    int j = jc * 256 + t;
    int base = b * Nn;
    float dy = g_dy[base + j], y0 = g_y0[base + j], invn = g_invn[base + j];
    float csum = 0.0f;
    for (int k = 0; k < 128; k++) {
        int i = iseg * 128 + k;
        float rmax = g_rmax[base + i];
        float rsuminv = g_rsuminv[base + i];
        float ix = (float)(i >> 5), iy = (float)(i & 31);
        float z = zval(ix, iy, dy, y0, invn);
        float s1 = __expf(z - rmax) * rsuminv;
        float E = __expf(1.0f - s1);
        csum += E;
        g_A[((size_t)base + i) * Nn + j] = f2bf(E);
    }
    atomicAdd(&g_csum[base + j], csum);
}

// f_src fp32 -> bf16 scaled by 1/csum[b][j] (folds the column-softmax denominator
// into the B operand). Grid 9216: lin&7 = b = XCD.
__global__ void convert_fsrc_kernel(const float* __restrict__ f) {
    int lin = blockIdx.x;
    int b = lin & 7;
    int rrow = lin >> 3;                       // 0..1151 (= channel c)
    int local = rrow * 1024 + threadIdx.x * 4; // element offset within batch
    int j = threadIdx.x * 4;
    size_t off = (size_t)b * Cn * Nn + local;
    float4 v = *(const float4*)(f + off);
    float4 cs = *(const float4*)&g_csum[b * Nn + j];
    ushort4 u;
    u.x = f2bf(v.x / cs.x);
    u.y = f2bf(v.y / cs.y);
    u.z = f2bf(v.z / cs.z);
    u.w = f2bf(v.w / cs.w);
    *(ushort4*)&g_fb[off] = u;
}

// out[b,i,c] = sum_j E[b,i,j] * fb_scaled[b,c,j]  — both operands K(j)-contiguous.
// 128(i) x 128(c) tile, BK=32, 4 waves, each wave 64x64 via 4x4 mfma_16x16x32.
// 1D grid, lin&7 = b = XCD: per-batch A (2 MB) + fb (2.36 MB) stay in that XCD's 4 MB L2.
#define BM 128
#define BNc 128
#define BK 32

__launch_bounds__(256) __global__ void gemm_kernel(float* __restrict__ out) {
    __shared__ unsigned short As[BM * BK];
    __shared__ unsigned short Bs[BNc * BK];
    int lin = blockIdx.x;
    int b = lin & 7;
    int s = lin >> 3;          // 0..71
    int it = s / 9;
    int ct = s - it * 9;
    int i0 = it * BM;
    int c0 = ct * BNc;
    int t = threadIdx.x;
    int w = t >> 6, L = t & 63;
    int wm = w >> 1, wn = w & 1;
    const unsigned short* Ab = g_A + (size_t)b * Nn * Nn + (size_t)i0 * Nn;
    const unsigned short* Fb = g_fb + (size_t)b * Cn * Nn + (size_t)c0 * Nn;
    f32x4 acc[4][4] = {};
    for (int kt = 0; kt < Nn; kt += BK) {
        __syncthreads();  // previous tile consumed
#pragma unroll
        for (int h = 0; h < 2; h++) {
            int chunk = (h * 4 + w) * 64 + L;       // 0..511, 16B each
            int r = chunk >> 2;                     // tile row 0..127
            int gq = (chunk & 3) ^ ((r >> 1) & 3);  // swizzled global k-quad
            const unsigned short* ga = Ab + (size_t)r * Nn + kt + gq * 8;
            const unsigned short* gb = Fb + (size_t)r * Nn + kt + gq * 8;
            __builtin_amdgcn_global_load_lds(
                (const __attribute__((address_space(1))) unsigned int*)ga,
                (__attribute__((address_space(3))) unsigned int*)(As + chunk * 8), 16, 0, 0);
            __builtin_amdgcn_global_load_lds(
                (const __attribute__((address_space(1))) unsigned int*)gb,
                (__attribute__((address_space(3))) unsigned int*)(Bs + chunk * 8), 16, 0, 0);
        }
        __syncthreads();  // vmcnt(0) drain + barrier
        short8 af[4], bf[4];
        int lrow = L & 15, quad = L >> 4;
#pragma unroll
        for (int mt = 0; mt < 4; mt++) {
            int r = wm * 64 + mt * 16 + lrow;
            int q = quad ^ ((r >> 1) & 3);
            af[mt] = *(const short8*)(As + r * BK + q * 8);
        }
#pragma unroll
        for (int nt = 0; nt < 4; nt++) {
            int r = wn * 64 + nt * 16 + lrow;
            int q = quad ^ ((r >> 1) & 3);
            bf[nt] = *(const short8*)(Bs + r * BK + q * 8);
        }
#pragma unroll
        for (int mt = 0; mt < 4; mt++)
#pragma unroll
            for (int nt = 0; nt < 4; nt++)
                acc[mt][nt] =
                    __builtin_amdgcn_mfma_f32_16x16x32_bf16(af[mt], bf[nt], acc[mt][nt], 0, 0, 0);
    }
    // Epilogue: D col=lane&15, row=(lane>>4)*4+reg  [m89-verified]
    int col = L & 15, quad = L >> 4;
#pragma unroll
    for (int mt = 0; mt < 4; mt++)
#pragma unroll
        for (int rg = 0; rg < 4; rg++) {
            int i = i0 + wm * 64 + mt * 16 + quad * 4 + rg;
            float* orow = out + ((size_t)b * Nn + i) * Cn + c0 + wn * 64;
#pragma unroll
            for (int nt = 0; nt < 4; nt++) orow[nt * 16 + col] = acc[mt][nt][rg];
        }
}

extern "C" void kernel_launch(void* const* d_in, const int* in_sizes, int n_in,
                              void* d_out, int out_size, void* d_ws, size_t ws_size,
                              hipStream_t stream) {
    (void)in_sizes; (void)n_in; (void)d_ws; (void)ws_size; (void)out_size;
    const float* f_src = (const float*)d_in[1];  // d_in[0] = f_tar unused by reference
    const float* K1 = (const float*)d_in[2];
    const float* K2 = (const float*)d_in[3];
    const float* R = (const float*)d_in[4];
    const float* t = (const float*)d_in[5];
    float* out = (float*)d_out;

    setup_kernel<<<dim3(Bn), dim3(256), 0, stream>>>(K1, K2, R, t);
    rowstats_kernel<<<dim3(2048), dim3(256), 0, stream>>>();
    colE_kernel<<<dim3(256), dim3(256), 0, stream>>>();
    convert_fsrc_kernel<<<dim3(Bn * Cn), dim3(256), 0, stream>>>(f_src);
    gemm_kernel<<<dim3(Bn * (Nn / BM) * (Cn / BNc)), dim3(256), 0, stream>>>(out);
}